// Round 4
// baseline (279.627 us; speedup 1.0000x reference)
//
#include <hip/hip_runtime.h>

// Wavelet analysis(stride2) + synthesis(transposed) fused into two 18-tap
// polyphase FIRs applied directly to the input:
//   even p: ya[p] = sum_d We[d]*sig_m[p+d-8]
//   odd  p: ya[p] = sum_d Wo[d]*sig_m[p+d-9]
//
// v3b: 16 outputs per thread from one 36-float register window (9
// independent float4 loads, 4 float4 stores). Even/odd output pairs
// computed as f2 accumulators sharing one splatted window operand ->
// v_pk_fma_f32; the pair is contiguous in memory. Nontemporal stores (via
// native ext_vector_type — HIP float4 class is rejected by the builtin)
// keep the reused input from being evicted by the write-once output.

typedef float f2 __attribute__((ext_vector_type(2)));
typedef float f4 __attribute__((ext_vector_type(4)));

#define L_SIG 524288
#define T_OUT 16                      // outputs per thread
#define SPAN  (256 * T_OUT)           // 4096 outputs per block

constexpr float RL[10] = {
    0.160102397974125f,   0.6038292697974729f,  0.7243085284385744f,
    0.13842814590110342f, -0.24229488706619015f, -0.03224486958502952f,
    0.07757149384006515f, -0.006241490213011705f, -0.012580751999015526f,
    0.003335725285001549f};

struct Coef { float we[18]; float wo[18]; };

constexpr Coef make_coef() {
    Coef c{};
    for (int d = 0; d < 18; ++d) {
        float se = 0.f, so = 0.f;
        for (int j = 0; j < 5; ++j) {
            int i = d - 2 * j;               // REC_LO tap index
            if (i >= 0 && i < 10) {
                se += RL[8 - 2 * j] * RL[i]; // DEC_LO[2j+1] = RL[8-2j]
                so += RL[9 - 2 * j] * RL[i]; // DEC_LO[2j]   = RL[9-2j]
            }
        }
        c.we[d] = se;
        c.wo[d] = so;
    }
    return c;
}

constexpr Coef CF = make_coef();

__global__ __launch_bounds__(256)
void wavelet_v3_kernel(const float* __restrict__ x, float* __restrict__ out) {
    const int batch = blockIdx.y;
    const int p0    = blockIdx.x * SPAN;
    const float* xb = x   + (size_t)batch * L_SIG;
    float*       ob = out + (size_t)batch * L_SIG;

    const int q = p0 + T_OUT * threadIdx.x;   // first output index (mult of 16)

    // Register window w[i] = sig_m[q - 8 + i], i in [0, 36)
    float w[36];

    const bool edge = (blockIdx.x == 0) || (blockIdx.x == gridDim.x - 1);
    if (edge) {
#pragma unroll
        for (int i = 0; i < 36; ++i) {
            int k = q - 8 + i;
            k = (k < 0) ? (-1 - k) : ((k >= L_SIG) ? (2 * L_SIG - 1 - k) : k);
            w[i] = xb[k];
        }
    } else {
        // q-8 is a multiple of 4 floats -> 16B aligned. 9 independent loads.
        const f4* a4 = (const f4*)(xb + q - 8);
#pragma unroll
        for (int r = 0; r < 9; ++r) {
            f4 f = a4[r];
            w[4 * r + 0] = f.x; w[4 * r + 1] = f.y;
            w[4 * r + 2] = f.z; w[4 * r + 3] = f.w;
        }
    }

    // Packed coefficients: cf[d] = (We[d], Wo[d]).
    f2 acc[8];
#pragma unroll
    for (int k = 0; k < 8; ++k) acc[k] = (f2)0.f;

#pragma unroll
    for (int d = 0; d < 18; ++d) {
        f2 cf; cf[0] = CF.we[d]; cf[1] = CF.wo[d];
#pragma unroll
        for (int k = 0; k < 8; ++k) {
            acc[k] += cf * w[2 * k + d];   // outputs (q+2k, q+2k+1)
        }
    }

    f4* o4 = (f4*)(ob + q);
#pragma unroll
    for (int k = 0; k < 4; ++k) {
        f4 o;
        o.x = acc[2 * k][0];     o.y = acc[2 * k][1];
        o.z = acc[2 * k + 1][0]; o.w = acc[2 * k + 1][1];
        __builtin_nontemporal_store(o, o4 + k);
    }
}

extern "C" void kernel_launch(void* const* d_in, const int* in_sizes, int n_in,
                              void* d_out, int out_size, void* d_ws, size_t ws_size,
                              hipStream_t stream) {
    const float* x = (const float*)d_in[0];
    float* out     = (float*)d_out;

    const int B = in_sizes[0] / L_SIG;        // 64
    dim3 grid(L_SIG / SPAN, B);               // (128, 64)
    wavelet_v3_kernel<<<grid, 256, 0, stream>>>(x, out);
}